// Round 7
// baseline (358.259 us; speedup 1.0000x reference)
//
#include <hip/hip_runtime.h>
#include <math.h>

// ---------------------------------------------------------------------------
// TemporalSSMPatchwise: b=8,t=15,H=480,W=640, PS=8 -> hp=60,wp=80, n=4800
// d=64, P=32, pp=64.  N_seq = 38400.
// Transpose-free dataflow: weights are MFMA A-operands (pre-permuted rows),
// activations are B-operands.  chan(nt,qd,r) = (nt>>1)*32+qd*8+(nt&1)*4+r;
// D-output register layout of one matmul IS the B-operand layout of the next.
// MFMA 16x16x32 bf16: A[m=lane&15][k=qd*8+j], B[k=qd*8+j][n=lane&15],
// D: col=lane&15, row=qd*4+reg (m89/m91-verified).
//
// v7: DEPTH-3 REGISTER PIPELINE, ZERO LDS, ZERO BARRIERS.
// Evidence v0-v6: scan period ~= load-latency / prefetch-depth (8.3us@1-deep,
// 5.2-6.3us@2-deep) regardless of barriers/granularity/LDS -> latency-bound,
// not BW-bound.  Scan weights (16 frags: W_embed 0..7 + Bu' 8..15) live in
// 64 VGPRs; x loads go per-lane direct to 3 statically-named register slots
// (A/B/C; 15 = 3x5 -> clean rotation, rule-#20-safe).  No LDS, no barriers,
// no manual waitcnt: compiler emits exact counted vmcnt waits on register
// deps, loads for t+3 issue right after slot t's pack frees the regs.
// Head frags (16..47) + W_out frags read from global (L2-hot, once/wave).
// k0, frag images, head math, fused W_out epilogue unchanged.
// ---------------------------------------------------------------------------

typedef __attribute__((ext_vector_type(8))) short short8;
typedef __attribute__((ext_vector_type(4))) float f32x4;

#define MFMA16(a, b, c) __builtin_amdgcn_mfma_f32_16x16x32_bf16((a), (b), (c), 0, 0, 0)

__device__ __forceinline__ short f2bf(float f) {
  union { float f; unsigned u; } v; v.f = f;
  unsigned r = (v.u + 0x7fffu + ((v.u >> 16) & 1u)) >> 16;  // RNE
  return (short)r;
}
__device__ __forceinline__ float geluf(float x) {
  return 0.5f * x * (1.0f + erff(x * 0.70710678118654752f));
}
// pack two C-layout f32x4 tiles (2kt, 2kt+1) into one bf16 B-operand frag
__device__ __forceinline__ short8 packfrag(const f32x4& a, const f32x4& b) {
  short8 o;
  o[0] = f2bf(a[0]); o[1] = f2bf(a[1]); o[2] = f2bf(a[2]); o[3] = f2bf(a[3]);
  o[4] = f2bf(b[0]); o[5] = f2bf(b[1]); o[6] = f2bf(b[2]); o[7] = f2bf(b[3]);
  return o;
}
// weight-row permutation: A-row a = i*16+m  ->  actual channel
__device__ __forceinline__ int ecmap(int i, int m) {
  return (i >> 1) * 32 + (m >> 2) * 8 + (i & 1) * 4 + (m & 3);
}
__device__ __forceinline__ void bbar_factors(const float* Lre, const float* Lim,
                                             const float* lstep, int p,
                                             float& fre, float& fim) {
  float st = expf(lstep[p]);
  float lr = Lre[p], li = Lim[p];
  float er = expf(lr * st);
  float lbr = er * cosf(li * st), lbi = er * sinf(li * st);
  float u = lbr - 1.0f, v = lbi;
  float den = lr * lr + li * li;
  fre = (u * lr + v * li) / den;
  fim = (v * lr - u * li) / den;
}

// ---------------------------------------------------------------------------
// K0: pack 176 A-operand fragments (1 KB each) + bu0.
// ids: 0..7 W_embed | 8..15 Bbar'(g1-folded) | 16..23 Cc2(mask-folded)
//      24..39 W_enc | 40..47 W_dec | 48..175 W_out (natural rows)
// frag(i,kt) value[j] at lane(qd,m): A[i*16+m][k=kt*32+qd*8+j]
// ---------------------------------------------------------------------------
__global__ __launch_bounds__(256) void k0_prep(
    const float* __restrict__ W_embed, const float* __restrict__ g1,
    const float* __restrict__ be1, const float* __restrict__ Lre,
    const float* __restrict__ Lim, const float* __restrict__ Bre,
    const float* __restrict__ Bim, const float* __restrict__ Cre,
    const float* __restrict__ Cim, const float* __restrict__ lstep,
    const float* __restrict__ W_enc, const float* __restrict__ W_dec,
    const float* __restrict__ W_out, short* __restrict__ wimg,
    float* __restrict__ bu0) {
  const int bid = blockIdx.x;
  if (bid == 44) {  // bu0[q] = sum_d beta1[d] * Bbar_comp[p][d]
    int q = threadIdx.x;
    if (q < 64) {
      int c = q >> 5, p = q & 31;
      float fre, fim; bbar_factors(Lre, Lim, lstep, p, fre, fim);
      float s = 0.f;
      for (int d = 0; d < 64; ++d) {
        float br = Bre[p * 64 + d], bi = Bim[p * 64 + d];
        float val = c ? (fre * bi + fim * br) : (fre * br - fim * bi);
        s += be1[d] * val;
      }
      bu0[q] = s;
    }
    return;
  }
  const int w = threadIdx.x >> 6, lane = threadIdx.x & 63;
  const int m = lane & 15, qd = lane >> 4;
  const int f = bid * 4 + w;
  short v[8];
  if (f < 8) {
    int i = f >> 1, kt = f & 1, chan = ecmap(i, m), k0 = kt * 32 + qd * 8;
#pragma unroll
    for (int j = 0; j < 8; ++j) v[j] = f2bf(W_embed[chan * 64 + k0 + j]);
  } else if (f < 16) {
    int fi = f - 8, i = fi >> 1, kt = fi & 1;
    int comp = i & 1, p = (i >> 1) * 16 + m, d0 = kt * 32 + qd * 8;
    float fre, fim; bbar_factors(Lre, Lim, lstep, p, fre, fim);
#pragma unroll
    for (int j = 0; j < 8; ++j) {
      int d = d0 + j;
      float br = Bre[p * 64 + d], bi = Bim[p * 64 + d];
      float val = comp ? (fre * bi + fim * br) : (fre * br - fim * bi);
      v[j] = f2bf(g1[d] * val);
    }
  } else if (f < 24) {
    int fi = f - 16, i = fi >> 1, kt = fi & 1, chan = ecmap(i, m);
#pragma unroll
    for (int j = 0; j < 8; ++j) {
      int comp = j >> 2, p = kt * 16 + qd * 4 + (j & 3);
      float stp = expf(lstep[p]);
      float fr = stp * fabsf(Lim[p]) * (1.0f / 6.28318530717958648f);
      float msk = (fr < 0.5f) ? 1.f : 0.f;
      float val = comp ? -Cim[chan * 32 + p] * msk : Cre[chan * 32 + p] * msk;
      v[j] = f2bf(val);
    }
  } else if (f < 40) {
    int fi = f - 24, i = fi >> 1, kt = fi & 1;
    int row = (i < 4) ? ecmap(i, m) : 64 + ecmap(i - 4, m);
#pragma unroll
    for (int j = 0; j < 8; ++j) v[j] = f2bf(W_enc[row * 64 + kt * 32 + qd * 8 + j]);
  } else if (f < 48) {
    int fi = f - 40, i = fi >> 1, kt = fi & 1, row = ecmap(i, m);
#pragma unroll
    for (int j = 0; j < 8; ++j) v[j] = f2bf(W_dec[row * 64 + kt * 32 + qd * 8 + j]);
  } else {
    int fi = f - 48, i = fi >> 1, kt = fi & 1, row = i * 16 + m;  // natural
#pragma unroll
    for (int j = 0; j < 8; ++j) v[j] = f2bf(W_out[row * 64 + kt * 32 + qd * 8 + j]);
  }
  short8 sv;
#pragma unroll
  for (int j = 0; j < 8; ++j) sv[j] = v[j];
  *(short8*)&wimg[(f * 64 + lane) * 8] = sv;
}

// ---------------------------------------------------------------------------
// K1: embed -> LN1 -> Bu -> scan -> head(MLP) -> LN3 -> W_out -> y.
// 256 thr = 4 independent waves, 16 seqs/wave, grid 600.  NO LDS.
// ---------------------------------------------------------------------------

// load x slot for time T: 4 f32x4 per lane (rows qd and 4+qd of lane's patch)
#define LOADX(X, T)                                                           \
  {                                                                           \
    const float* rp_ = xbase + (T) * 307200;                                  \
    X[0] = *(const f32x4*)rp_;                                                \
    X[1] = *(const f32x4*)(rp_ + 4);                                          \
    X[2] = *(const f32x4*)(rp_ + 2560);                                       \
    X[3] = *(const f32x4*)(rp_ + 2564);                                       \
  }

// one scan step consuming slot X at time T; refills X with time T+3
#define BODY(X, T)                                                            \
  {                                                                           \
    short8 pa0 = packfrag(X[0], X[1]);                                        \
    short8 pa1 = packfrag(X[2], X[3]);                                        \
    if ((T) + 3 < 15) LOADX(X, (T) + 3);                                      \
    f32x4 c1[4];                                                              \
    _Pragma("unroll") for (int i = 0; i < 4; ++i) {                           \
      f32x4 acc = MFMA16(we[i * 2], pa0, zf);                                 \
      acc = MFMA16(we[i * 2 + 1], pa1, acc);                                  \
      c1[i] = acc + bec[i];                                                   \
    }                                                                         \
    float sm = 0.f, sq = 0.f;                                                 \
    _Pragma("unroll") for (int nt = 0; nt < 4; ++nt)                          \
        _Pragma("unroll") for (int i = 0; i < 4; ++i) {                       \
      sm += c1[nt][i];                                                        \
      sq += c1[nt][i] * c1[nt][i];                                            \
    }                                                                         \
    sm += __shfl_xor(sm, 16); sq += __shfl_xor(sq, 16);                       \
    sm += __shfl_xor(sm, 32); sq += __shfl_xor(sq, 32);                       \
    float mean = sm * 0.015625f;                                              \
    float rstd = rsqrtf(sq * 0.015625f - mean * mean + 1e-5f);                \
    _Pragma("unroll") for (int nt = 0; nt < 4; ++nt)                          \
        xh[nt] = (c1[nt] - mean) * rstd;                                      \
    short8 xa0 = packfrag(xh[0], xh[1]);                                      \
    short8 xa1 = packfrag(xh[2], xh[3]);                                      \
    _Pragma("unroll") for (int k = 0; k < 2; ++k) {                           \
      f32x4 re = state[2 * k], im = state[2 * k + 1];                         \
      state[2 * k]     = lbr[k] * re - lbi[k] * im + bu0c[2 * k];             \
      state[2 * k + 1] = lbr[k] * im + lbi[k] * re + bu0c[2 * k + 1];         \
    }                                                                         \
    _Pragma("unroll") for (int i = 0; i < 4; ++i) {                           \
      state[i] = MFMA16(we[8 + i * 2], xa0, state[i]);                        \
      state[i] = MFMA16(we[8 + i * 2 + 1], xa1, state[i]);                    \
    }                                                                         \
  }

__global__ __launch_bounds__(256) void k1_fused(
    const float* __restrict__ x, const short* __restrict__ wimg_g,
    const float* __restrict__ bu0_g, const float* __restrict__ Lre,
    const float* __restrict__ Lim, const float* __restrict__ lstep,
    const float* __restrict__ g1, const float* __restrict__ be1,
    const float* __restrict__ bemb, const float* __restrict__ Dv,
    const float* __restrict__ g2, const float* __restrict__ be2,
    const float* __restrict__ g3, const float* __restrict__ be3,
    const float* __restrict__ b_out, float* __restrict__ y) {
#define GW(id) (*(const short8*)&wimg_g[(id) * 512 + lane * 8])

  const int tid = threadIdx.x;
  const int wv = tid >> 6, lane = tid & 63;
  const int s = lane & 15, qd = lane >> 4;

  // ---- scan weights (frags 0..15) into registers: 16 x short8 = 64 VGPR ----
  short8 we[16];
#pragma unroll
  for (int i = 0; i < 16; ++i) we[i] = GW(i);

  // ---- per-lane constants ----
  int cb[4];
  f32x4 bec[4], bu0c[4];
#pragma unroll
  for (int nt = 0; nt < 4; ++nt) {
    cb[nt] = (nt >> 1) * 32 + qd * 8 + (nt & 1) * 4;
    bec[nt] = *(const f32x4*)(bemb + cb[nt]);
    bu0c[nt] = *(const f32x4*)(bu0_g + (nt & 1) * 32 + (nt >> 1) * 16 + qd * 4);
  }
  f32x4 lbr[2], lbi[2];
#pragma unroll
  for (int k = 0; k < 2; ++k)
#pragma unroll
    for (int r = 0; r < 4; ++r) {
      int p = k * 16 + qd * 4 + r;
      float st = expf(lstep[p]);
      float er = expf(Lre[p] * st);
      lbr[k][r] = er * cosf(Lim[p] * st);
      lbi[k][r] = er * sinf(Lim[p] * st);
    }

  // ---- per-lane x geometry (v0 dense pattern: 4x512B runs per instr) ----
  const int sbase = (blockIdx.x * 4 + wv) * 16;
  const int b_i = sbase / 4800;
  const int pr = sbase % 4800;
  const int ph = pr / 80;
  const int pw0 = pr % 80;
  const float* xbase = x + ((b_i * 15) * 480 + ph * 8 + qd) * 640 + (pw0 + s) * 8;

  const f32x4 zf = {0.f, 0.f, 0.f, 0.f};
  f32x4 state[4] = {zf, zf, zf, zf};
  f32x4 xh[4];

  // ---- depth-3 register pipeline: slots A,B,C; 15 = 3 x 5 ----
  f32x4 xsA[4], xsB[4], xsC[4];
  LOADX(xsA, 0);
  LOADX(xsB, 1);
  LOADX(xsC, 2);

  for (int tt = 0; tt < 5; ++tt) {
    const int t0 = tt * 3;
    BODY(xsA, t0 + 0);
    BODY(xsB, t0 + 1);
    BODY(xsC, t0 + 2);
  }

  // ---- head at t = 14 (frags from global, L2-hot) ----
  f32x4 g1c[4], b1c[4], Dc[4], g2c[4], b2c[4];
#pragma unroll
  for (int nt = 0; nt < 4; ++nt) {
    g1c[nt] = *(const f32x4*)(g1 + cb[nt]);
    b1c[nt] = *(const f32x4*)(be1 + cb[nt]);
    Dc[nt] = *(const f32x4*)(Dv + cb[nt]);
    g2c[nt] = *(const f32x4*)(g2 + cb[nt]);
    b2c[nt] = *(const f32x4*)(be2 + cb[nt]);
  }
  f32x4 fxl[4];
#pragma unroll
  for (int nt = 0; nt < 4; ++nt) fxl[nt] = xh[nt] * g1c[nt] + b1c[nt];

  short8 xsa0 = packfrag(state[0], state[1]);
  short8 xsa1 = packfrag(state[2], state[3]);
  f32x4 xbv[4];
#pragma unroll
  for (int i = 0; i < 4; ++i) {
    f32x4 acc = fxl[i] * Dc[i];
    acc = MFMA16(GW(16 + i * 2), xsa0, acc);
    acc = MFMA16(GW(16 + i * 2 + 1), xsa1, acc);
#pragma unroll
    for (int r = 0; r < 4; ++r) xbv[i][r] = geluf(acc[r]) + fxl[i][r];
  }
  float sm2 = 0.f, sq2 = 0.f;
#pragma unroll
  for (int nt = 0; nt < 4; ++nt)
#pragma unroll
    for (int i = 0; i < 4; ++i) { sm2 += xbv[nt][i]; sq2 += xbv[nt][i] * xbv[nt][i]; }
  sm2 += __shfl_xor(sm2, 16); sq2 += __shfl_xor(sq2, 16);
  sm2 += __shfl_xor(sm2, 32); sq2 += __shfl_xor(sq2, 32);
  float mean2 = sm2 * 0.015625f;
  float rstd2 = rsqrtf(sq2 * 0.015625f - mean2 * mean2 + 1e-5f);
  f32x4 fx2[4];
#pragma unroll
  for (int nt = 0; nt < 4; ++nt)
    fx2[nt] = (xbv[nt] - mean2) * rstd2 * g2c[nt] + b2c[nt];

  short8 fa0 = packfrag(fx2[0], fx2[1]);
  short8 fa1 = packfrag(fx2[2], fx2[3]);
  f32x4 e[8];
#pragma unroll
  for (int i = 0; i < 8; ++i) {
    f32x4 acc = MFMA16(GW(24 + i * 2), fa0, zf);
    e[i] = MFMA16(GW(24 + i * 2 + 1), fa1, acc);
  }
  f32x4 hv[4];
#pragma unroll
  for (int nt = 0; nt < 4; ++nt)
#pragma unroll
    for (int i = 0; i < 4; ++i) hv[nt][i] = e[nt][i] * geluf(e[nt + 4][i]);

  short8 ha0 = packfrag(hv[0], hv[1]);
  short8 ha1 = packfrag(hv[2], hv[3]);
  f32x4 xo[4];
#pragma unroll
  for (int i = 0; i < 4; ++i) {
    f32x4 acc = fx2[i];
    acc = MFMA16(GW(40 + i * 2), ha0, acc);
    xo[i] = MFMA16(GW(40 + i * 2 + 1), ha1, acc);
  }

  // ---- fused k2: LN3 + W_out GEMM + pixel-shuffle store ----
  float sm3 = 0.f, sq3 = 0.f;
#pragma unroll
  for (int nt = 0; nt < 4; ++nt)
#pragma unroll
    for (int i = 0; i < 4; ++i) { sm3 += xo[nt][i]; sq3 += xo[nt][i] * xo[nt][i]; }
  sm3 += __shfl_xor(sm3, 16); sq3 += __shfl_xor(sq3, 16);
  sm3 += __shfl_xor(sm3, 32); sq3 += __shfl_xor(sq3, 32);
  float mean3 = sm3 * 0.015625f;
  float rstd3 = rsqrtf(sq3 * 0.015625f - mean3 * mean3 + 1e-5f);
  f32x4 z[4];
#pragma unroll
  for (int nt = 0; nt < 4; ++nt) {
    f32x4 g3c = *(const f32x4*)(g3 + cb[nt]);
    f32x4 b3c = *(const f32x4*)(be3 + cb[nt]);
    z[nt] = (xo[nt] - mean3) * rstd3 * g3c + b3c;
  }
  short8 za = packfrag(z[0], z[1]);
  short8 zb = packfrag(z[2], z[3]);

  const int seq = sbase + s;
  const int bi2 = seq / 4800, prr = seq % 4800;
  const int phh = prr / 80, pww = prr % 80;
  const int obase = (bi2 * 16 * 480 + phh * 8) * 640 + pww * 8;
  const short* wob = wimg_g + 48 * 512;  // W_out frag images (128KB, L2-hot)

#pragma unroll 4
  for (int ntg = 0; ntg < 64; ++ntg) {
    short8 a0 = *(const short8*)&wob[(ntg * 2 + 0) * 512 + lane * 8];
    short8 a1 = *(const short8*)&wob[(ntg * 2 + 1) * 512 + lane * 8];
    int o0 = ntg * 16 + qd * 4;
    f32x4 acc = *(const f32x4*)(b_out + o0);
    acc = MFMA16(a0, za, acc);
    acc = MFMA16(a1, zb, acc);
    int c = o0 >> 6, pi = (o0 >> 3) & 7, pj = o0 & 7;
    *(f32x4*)&y[obase + c * 307200 + pi * 640 + pj] = acc;
  }
#undef GW
}

// ---------------------------------------------------------------------------
extern "C" void kernel_launch(void* const* d_in, const int* in_sizes, int n_in,
                              void* d_out, int out_size, void* d_ws, size_t ws_size,
                              hipStream_t stream) {
  const float* x       = (const float*)d_in[0];
  const float* W_embed = (const float*)d_in[1];
  const float* b_embed = (const float*)d_in[2];
  const float* g1      = (const float*)d_in[3];
  const float* beta1   = (const float*)d_in[4];
  const float* Lre     = (const float*)d_in[5];
  const float* Lim     = (const float*)d_in[6];
  const float* Bre     = (const float*)d_in[7];
  const float* Bim     = (const float*)d_in[8];
  const float* Cre     = (const float*)d_in[9];
  const float* Cim     = (const float*)d_in[10];
  const float* Dv      = (const float*)d_in[11];
  const float* lstep   = (const float*)d_in[12];
  const float* g2      = (const float*)d_in[13];
  const float* beta2   = (const float*)d_in[14];
  const float* W_enc   = (const float*)d_in[15];
  const float* W_dec   = (const float*)d_in[16];
  const float* g3      = (const float*)d_in[17];
  const float* beta3   = (const float*)d_in[18];
  const float* W_out   = (const float*)d_in[19];
  const float* b_out   = (const float*)d_in[20];
  float* y = (float*)d_out;

  short* wimg = (short*)d_ws;                          // 176 KB frag images
  float* bu0 = (float*)((char*)d_ws + 176 * 1024);     // 256 B

  k0_prep<<<dim3(45), dim3(256), 0, stream>>>(W_embed, g1, beta1, Lre, Lim,
                                              Bre, Bim, Cre, Cim, lstep,
                                              W_enc, W_dec, W_out, wimg, bu0);
  k1_fused<<<dim3(600), dim3(256), 0, stream>>>(x, wimg, bu0, Lre, Lim, lstep,
                                                g1, beta1, b_embed, Dv, g2,
                                                beta2, g3, beta3, b_out, y);
}